// Round 6
// baseline (1294.000 us; speedup 1.0000x reference)
//
#include <hip/hip_runtime.h>
#include <stdint.h>

#define HEADS 8
#define DIM 8
#define HD 64
#define F_IN 128
#define T_SEQ 2048
#define GHID 16

// K1: xp = x @ W_gat  [N,64]; a_src[n,h] = sum_d xp[n,h,d]*att_src[h,d]; same a_dst.
__global__ __launch_bounds__(256) void k1_xp(
        const float* __restrict__ x, const float* __restrict__ Wg,
        const float* __restrict__ att_s, const float* __restrict__ att_d,
        float* __restrict__ xp, float* __restrict__ a_src, float* __restrict__ a_dst) {
    __shared__ float Wl[F_IN * HD];      // 32 KB
    __shared__ float xs[4][F_IN];        // 2 KB
    __shared__ float atts[HD], attd[HD];
    int t = threadIdx.x;
    for (int i = t * 4; i < F_IN * HD; i += 256 * 4)
        *(float4*)&Wl[i] = *(const float4*)&Wg[i];
    if (t < HD) { atts[t] = att_s[t]; attd[t] = att_d[t]; }
    int n0 = blockIdx.x * 4;
    {
        int ln = t >> 6, k = t & 63;
        *(float2*)&xs[ln][k * 2] = *(const float2*)&x[(size_t)(n0 + ln) * F_IN + k * 2];
    }
    __syncthreads();
    int ln = t >> 6, k = t & 63;
    float acc = 0.f;
    #pragma unroll 8
    for (int f = 0; f < F_IN; ++f) acc += xs[ln][f] * Wl[f * HD + k];
    int n = n0 + ln;
    xp[(size_t)n * HD + k] = acc;
    float ps = acc * atts[k];
    float pd = acc * attd[k];
    #pragma unroll
    for (int off = 1; off < 8; off <<= 1) {
        ps += __shfl_xor(ps, off);
        pd += __shfl_xor(pd, off);
    }
    if ((k & 7) == 0) {
        a_src[n * HEADS + (k >> 3)] = ps;
        a_dst[n * HEADS + (k >> 3)] = pd;
    }
}

// K4 (fused softmax-denom + aggregation, no max-subtraction):
// per edge: e = exp(leakyrelu(a_src[s]+a_dst[d])); denom[d][h] += e;
// agg[d][k] += xp[s][k] * e.   64 lanes per edge.
__global__ __launch_bounds__(256) void k4_agg(
        const int* __restrict__ ei, int E, int Etot,
        const float* __restrict__ a_src, const float* __restrict__ a_dst,
        const float* __restrict__ xp, float* __restrict__ denom,
        float* __restrict__ agg) {
    int t = blockIdx.x * 256 + threadIdx.x;
    int e = t >> 6;
    if (e >= Etot) return;
    int k = t & 63, h = k >> 3;
    int s, d;
    if (e < E) { s = ei[e]; d = ei[E + e]; } else { s = d = e - E; }
    float a = a_src[(size_t)s * 8 + h] + a_dst[(size_t)d * 8 + h];
    a = a > 0.f ? a : 0.2f * a;
    float ew = __expf(a);
    if ((k & 7) == 0) atomicAdd(&denom[(size_t)d * 8 + h], ew);
    float v = xp[(size_t)s * 64 + k];
    atomicAdd(&agg[(size_t)d * 64 + k], v * ew);
}

// K5: feat = relu(agg/denom + b_gat); gi4[n][j] = float4(i_r, i_z, i_n, 0)
// where i_g[j] = b_ih[g*16+j] + sum_f feat[f] * W_ih[(g*16+j)][f].
// Packed layout so k6 does ONE dwordx4 load per step per lane.
__global__ __launch_bounds__(256) void k5_gi(
        const float* __restrict__ agg, const float* __restrict__ denom,
        const float* __restrict__ b_gat,
        const float* __restrict__ W_ih, const float* __restrict__ b_ih,
        float* __restrict__ gi4) {
    __shared__ float Wl[48 * 65];
    __shared__ float fl[16][65];
    __shared__ float bg[64], bi[48];
    int t = threadIdx.x;
    for (int i = t; i < 48 * 64; i += 256) Wl[(i >> 6) * 65 + (i & 63)] = W_ih[i];
    if (t < 64) bg[t] = b_gat[t];
    if (t < 48) bi[t] = b_ih[t];
    int n0 = blockIdx.x * 16;
    __syncthreads();
    for (int i = t; i < 16 * 64; i += 256) {
        int ln = i >> 6, k = i & 63;
        int n = n0 + ln;
        float den = denom[(size_t)n * 8 + (k >> 3)] + 1e-16f;
        float v = agg[(size_t)n * 64 + k] / den + bg[k];
        fl[ln][k] = v > 0.f ? v : 0.f;
    }
    __syncthreads();
    for (int o = t; o < 16 * 48; o += 256) {
        int ln = o / 48, g = o % 48;
        float acc = bi[g];
        #pragma unroll 8
        for (int f = 0; f < 64; ++f) acc += fl[ln][f] * Wl[g * 65 + f];
        int j = g & 15, gate = g >> 4;
        gi4[(size_t)(n0 + ln) * 64 + j * 4 + gate] = acc;
    }
}

// One GRU step. g = (i_r, i_z, i_n, pad) for this lane's unit j.
__device__ __forceinline__ void gru_step(
        const float4 g, const float* __restrict__ wr, const float* __restrict__ wz,
        const float* __restrict__ wn, float bhr, float bhz, float bhn,
        float* hs, float& hcur) {
    float r0 = 0.f, r1 = 0.f, r2 = 0.f, r3 = 0.f;
    float z0 = 0.f, z1 = 0.f, z2 = 0.f, z3 = 0.f;
    float n0 = 0.f, n1 = 0.f, n2 = 0.f, n3 = 0.f;
    #pragma unroll
    for (int k = 0; k < 16; k += 4) {
        r0 = fmaf(wr[k],     hs[k],     r0);
        r1 = fmaf(wr[k + 1], hs[k + 1], r1);
        r2 = fmaf(wr[k + 2], hs[k + 2], r2);
        r3 = fmaf(wr[k + 3], hs[k + 3], r3);
        z0 = fmaf(wz[k],     hs[k],     z0);
        z1 = fmaf(wz[k + 1], hs[k + 1], z1);
        z2 = fmaf(wz[k + 2], hs[k + 2], z2);
        z3 = fmaf(wz[k + 3], hs[k + 3], z3);
        n0 = fmaf(wn[k],     hs[k],     n0);
        n1 = fmaf(wn[k + 1], hs[k + 1], n1);
        n2 = fmaf(wn[k + 2], hs[k + 2], n2);
        n3 = fmaf(wn[k + 3], hs[k + 3], n3);
    }
    float rpre = ((r0 + r1) + (r2 + r3)) + bhr + g.x;
    float zpre = ((z0 + z1) + (z2 + z3)) + bhz + g.y;
    float npre = ((n0 + n1) + (n2 + n3)) + bhn;
    float r = 1.f / (1.f + __expf(-rpre));
    float z = 1.f / (1.f + __expf(-zpre));
    float np = g.z + r * npre;
    np = fminf(fmaxf(np, -15.f), 15.f);
    float e2 = __expf(-2.f * np);
    float nn = (1.f - e2) / (1.f + e2);
    hcur = fmaf(z, hcur - nn, nn);           // (1-z)*n + z*h
    #pragma unroll
    for (int k = 0; k < 16; ++k)
        hs[k] = __int_as_float(
            __builtin_amdgcn_readlane(__float_as_int(hcur), k));
}

// K6 v4: 8 waves/block (wave = one batch element), 2 waves/SIMD for TLP.
// One dwordx4 gi load per step, moving-pointer PF=8 pipeline, clean tail.
// h broadcast via v_readlane (SGPRs); no LDS, no barriers.
__global__ __launch_bounds__(512) void k6_gru(
        const float* __restrict__ gi4, const float* __restrict__ W_hh,
        const float* __restrict__ b_hh, const float* __restrict__ W_lin,
        const float* __restrict__ b_lin, float* __restrict__ out, int B) {
    int l = threadIdx.x & 63;
    int wv = threadIdx.x >> 6;
    int b = blockIdx.x * 8 + wv;
    int j = l & 15;

    float wr[16], wz[16], wn[16];
    #pragma unroll
    for (int k = 0; k < 16; ++k) {
        wr[k] = W_hh[j * 16 + k];
        wz[k] = W_hh[(16 + j) * 16 + k];
        wn[k] = W_hh[(32 + j) * 16 + k];
    }
    float bhr = b_hh[j], bhz = b_hh[16 + j], bhn = b_hh[32 + j];

    const float4* gp = (const float4*)gi4 + (size_t)b * T_SEQ * 16 + j;

    float hcur = 0.f;
    float hs[16];
    #pragma unroll
    for (int k = 0; k < 16; ++k) hs[k] = 0.f;

    const int PF = 8;
    float4 pf[PF];
    #pragma unroll
    for (int i = 0; i < PF; ++i) pf[i] = gp[(size_t)i * 16];
    const float4* gnext = gp + (size_t)PF * 16;

    for (int c = 0; c < T_SEQ - PF; c += PF) {
        #pragma unroll
        for (int u = 0; u < PF; ++u) {
            float4 g = pf[u];
            pf[u] = gnext[(size_t)u * 16];
            gru_step(g, wr, wz, wn, bhr, bhz, bhn, hs, hcur);
        }
        gnext += (size_t)PF * 16;
    }
    #pragma unroll
    for (int u = 0; u < PF; ++u)
        gru_step(pf[u], wr, wz, wn, bhr, bhz, bhn, hs, hcur);

    if (l == 0) {
        float acc = b_lin[0];
        #pragma unroll
        for (int k = 0; k < 16; ++k) acc += hs[k] * W_lin[k];
        out[b] = acc;
    }
    if (l < GHID) out[B + b * GHID + l] = hcur;
}

extern "C" void kernel_launch(void* const* d_in, const int* in_sizes, int n_in,
                              void* d_out, int out_size, void* d_ws, size_t ws_size,
                              hipStream_t stream) {
    const float* x      = (const float*)d_in[0];
    const int*   ei     = (const int*)d_in[1];
    // d_in[2] edge_attr: unused (edge_dim=None)
    const float* W_gat  = (const float*)d_in[3];
    const float* att_s  = (const float*)d_in[4];
    const float* att_d  = (const float*)d_in[5];
    const float* b_gat  = (const float*)d_in[6];
    const float* W_ih   = (const float*)d_in[7];
    const float* W_hh   = (const float*)d_in[8];
    const float* b_ih   = (const float*)d_in[9];
    const float* b_hh   = (const float*)d_in[10];
    const float* W_lin  = (const float*)d_in[11];
    const float* b_lin  = (const float*)d_in[12];
    float* out = (float*)d_out;

    int N = in_sizes[0] / F_IN;       // 65536
    int E = in_sizes[1] / 2;          // 1048576
    int Etot = E + N;                 // self-loops appended
    int B = N / T_SEQ;                // 32

    float* ws = (float*)d_ws;
    float* xp     = ws;                                   // N*64
    float* a_src  = xp + (size_t)N * 64;                  // N*8
    float* a_dst  = a_src + (size_t)N * 8;                // N*8
    float* denom  = a_dst + (size_t)N * 8;                // N*8
    float* agg    = denom + (size_t)N * 8;                // N*64
    float* gi4    = xp;   // aliases xp: xp dead after k4, k5 reads only agg/denom

    // zero denom + agg (contiguous): 2 + 16 MB
    hipMemsetAsync(denom, 0, (size_t)N * 72 * sizeof(float), stream);

    k1_xp<<<N / 4, 256, 0, stream>>>(x, W_gat, att_s, att_d, xp, a_src, a_dst);
    {
        long long tot = (long long)Etot * 64;
        int blocks = (int)((tot + 255) / 256);
        k4_agg<<<blocks, 256, 0, stream>>>(ei, E, Etot, a_src, a_dst, xp, denom, agg);
    }
    k5_gi<<<N / 16, 256, 0, stream>>>(agg, denom, b_gat, W_ih, b_ih, gi4);
    k6_gru<<<B / 8, 512, 0, stream>>>(gi4, W_hh, b_hh, W_lin, b_lin, out, B);
}

// Round 7
// 1293.046 us; speedup vs baseline: 1.0007x; 1.0007x over previous
//
#include <hip/hip_runtime.h>
#include <stdint.h>

#define HEADS 8
#define DIM 8
#define HD 64
#define F_IN 128
#define T_SEQ 2048
#define GHID 16

// K1: xp = x @ W_gat  [N,64]; a_src[n,h] = sum_d xp[n,h,d]*att_src[h,d]; same a_dst.
__global__ __launch_bounds__(256) void k1_xp(
        const float* __restrict__ x, const float* __restrict__ Wg,
        const float* __restrict__ att_s, const float* __restrict__ att_d,
        float* __restrict__ xp, float* __restrict__ a_src, float* __restrict__ a_dst) {
    __shared__ float Wl[F_IN * HD];      // 32 KB
    __shared__ float xs[4][F_IN];        // 2 KB
    __shared__ float atts[HD], attd[HD];
    int t = threadIdx.x;
    for (int i = t * 4; i < F_IN * HD; i += 256 * 4)
        *(float4*)&Wl[i] = *(const float4*)&Wg[i];
    if (t < HD) { atts[t] = att_s[t]; attd[t] = att_d[t]; }
    int n0 = blockIdx.x * 4;
    {
        int ln = t >> 6, k = t & 63;
        *(float2*)&xs[ln][k * 2] = *(const float2*)&x[(size_t)(n0 + ln) * F_IN + k * 2];
    }
    __syncthreads();
    int ln = t >> 6, k = t & 63;
    float acc = 0.f;
    #pragma unroll 8
    for (int f = 0; f < F_IN; ++f) acc += xs[ln][f] * Wl[f * HD + k];
    int n = n0 + ln;
    xp[(size_t)n * HD + k] = acc;
    float ps = acc * atts[k];
    float pd = acc * attd[k];
    #pragma unroll
    for (int off = 1; off < 8; off <<= 1) {
        ps += __shfl_xor(ps, off);
        pd += __shfl_xor(pd, off);
    }
    if ((k & 7) == 0) {
        a_src[n * HEADS + (k >> 3)] = ps;
        a_dst[n * HEADS + (k >> 3)] = pd;
    }
}

// K4 (fused softmax-denom + aggregation, no max-subtraction):
// per edge: e = exp(leakyrelu(a_src[s]+a_dst[d])); denom[d][h] += e;
// agg[d][k] += xp[s][k] * e.   64 lanes per edge.
__global__ __launch_bounds__(256) void k4_agg(
        const int* __restrict__ ei, int E, int Etot,
        const float* __restrict__ a_src, const float* __restrict__ a_dst,
        const float* __restrict__ xp, float* __restrict__ denom,
        float* __restrict__ agg) {
    int t = blockIdx.x * 256 + threadIdx.x;
    int e = t >> 6;
    if (e >= Etot) return;
    int k = t & 63, h = k >> 3;
    int s, d;
    if (e < E) { s = ei[e]; d = ei[E + e]; } else { s = d = e - E; }
    float a = a_src[(size_t)s * 8 + h] + a_dst[(size_t)d * 8 + h];
    a = a > 0.f ? a : 0.2f * a;
    float ew = __expf(a);
    if ((k & 7) == 0) atomicAdd(&denom[(size_t)d * 8 + h], ew);
    float v = xp[(size_t)s * 64 + k];
    atomicAdd(&agg[(size_t)d * 64 + k], v * ew);
}

// K5: feat = relu(agg/denom + b_gat); gi4[n][j] = float4(i_r, i_z, i_n, 0)
// where i_g[j] = b_ih[g*16+j] + sum_f feat[f] * W_ih[(g*16+j)][f].
// Packed layout so k6 does ONE dwordx4 load per step per lane.
__global__ __launch_bounds__(256) void k5_gi(
        const float* __restrict__ agg, const float* __restrict__ denom,
        const float* __restrict__ b_gat,
        const float* __restrict__ W_ih, const float* __restrict__ b_ih,
        float* __restrict__ gi4) {
    __shared__ float Wl[48 * 65];
    __shared__ float fl[16][65];
    __shared__ float bg[64], bi[48];
    int t = threadIdx.x;
    for (int i = t; i < 48 * 64; i += 256) Wl[(i >> 6) * 65 + (i & 63)] = W_ih[i];
    if (t < 64) bg[t] = b_gat[t];
    if (t < 48) bi[t] = b_ih[t];
    int n0 = blockIdx.x * 16;
    __syncthreads();
    for (int i = t; i < 16 * 64; i += 256) {
        int ln = i >> 6, k = i & 63;
        int n = n0 + ln;
        float den = denom[(size_t)n * 8 + (k >> 3)] + 1e-16f;
        float v = agg[(size_t)n * 64 + k] / den + bg[k];
        fl[ln][k] = v > 0.f ? v : 0.f;
    }
    __syncthreads();
    for (int o = t; o < 16 * 48; o += 256) {
        int ln = o / 48, g = o % 48;
        float acc = bi[g];
        #pragma unroll 8
        for (int f = 0; f < 64; ++f) acc += fl[ln][f] * Wl[g * 65 + f];
        int j = g & 15, gate = g >> 4;
        gi4[(size_t)(n0 + ln) * 64 + j * 4 + gate] = acc;
    }
}

// One GRU step. g = (i_r, i_z, i_n, pad) for this lane's unit j.
__device__ __forceinline__ void gru_step(
        const float4 g, const float* __restrict__ wr, const float* __restrict__ wz,
        const float* __restrict__ wn, float bhr, float bhz, float bhn,
        float* hs, float& hcur) {
    float r0 = 0.f, r1 = 0.f, r2 = 0.f, r3 = 0.f;
    float z0 = 0.f, z1 = 0.f, z2 = 0.f, z3 = 0.f;
    float n0 = 0.f, n1 = 0.f, n2 = 0.f, n3 = 0.f;
    #pragma unroll
    for (int k = 0; k < 16; k += 4) {
        r0 = fmaf(wr[k],     hs[k],     r0);
        r1 = fmaf(wr[k + 1], hs[k + 1], r1);
        r2 = fmaf(wr[k + 2], hs[k + 2], r2);
        r3 = fmaf(wr[k + 3], hs[k + 3], r3);
        z0 = fmaf(wz[k],     hs[k],     z0);
        z1 = fmaf(wz[k + 1], hs[k + 1], z1);
        z2 = fmaf(wz[k + 2], hs[k + 2], z2);
        z3 = fmaf(wz[k + 3], hs[k + 3], z3);
        n0 = fmaf(wn[k],     hs[k],     n0);
        n1 = fmaf(wn[k + 1], hs[k + 1], n1);
        n2 = fmaf(wn[k + 2], hs[k + 2], n2);
        n3 = fmaf(wn[k + 3], hs[k + 3], n3);
    }
    float rpre = ((r0 + r1) + (r2 + r3)) + bhr + g.x;
    float zpre = ((z0 + z1) + (z2 + z3)) + bhz + g.y;
    float npre = ((n0 + n1) + (n2 + n3)) + bhn;
    float r = 1.f / (1.f + __expf(-rpre));
    float z = 1.f / (1.f + __expf(-zpre));
    float np = g.z + r * npre;
    np = fminf(fmaxf(np, -15.f), 15.f);
    float e2 = __expf(-2.f * np);
    float nn = (1.f - e2) / (1.f + e2);
    hcur = fmaf(z, hcur - nn, nn);           // (1-z)*n + z*h
    #pragma unroll
    for (int k = 0; k < 16; ++k)
        hs[k] = __int_as_float(
            __builtin_amdgcn_readlane(__float_as_int(hcur), k));
}

// K6 v4: 8 waves/block (wave = one batch element), 2 waves/SIMD for TLP.
// One dwordx4 gi load per step, moving-pointer PF=8 pipeline, clean tail.
// h broadcast via v_readlane (SGPRs); no LDS, no barriers.
__global__ __launch_bounds__(512) void k6_gru(
        const float* __restrict__ gi4, const float* __restrict__ W_hh,
        const float* __restrict__ b_hh, const float* __restrict__ W_lin,
        const float* __restrict__ b_lin, float* __restrict__ out, int B) {
    int l = threadIdx.x & 63;
    int wv = threadIdx.x >> 6;
    int b = blockIdx.x * 8 + wv;
    int j = l & 15;

    float wr[16], wz[16], wn[16];
    #pragma unroll
    for (int k = 0; k < 16; ++k) {
        wr[k] = W_hh[j * 16 + k];
        wz[k] = W_hh[(16 + j) * 16 + k];
        wn[k] = W_hh[(32 + j) * 16 + k];
    }
    float bhr = b_hh[j], bhz = b_hh[16 + j], bhn = b_hh[32 + j];

    const float4* gp = (const float4*)gi4 + (size_t)b * T_SEQ * 16 + j;

    float hcur = 0.f;
    float hs[16];
    #pragma unroll
    for (int k = 0; k < 16; ++k) hs[k] = 0.f;

    const int PF = 8;
    float4 pf[PF];
    #pragma unroll
    for (int i = 0; i < PF; ++i) pf[i] = gp[(size_t)i * 16];
    const float4* gnext = gp + (size_t)PF * 16;

    for (int c = 0; c < T_SEQ - PF; c += PF) {
        #pragma unroll
        for (int u = 0; u < PF; ++u) {
            float4 g = pf[u];
            pf[u] = gnext[(size_t)u * 16];
            gru_step(g, wr, wz, wn, bhr, bhz, bhn, hs, hcur);
        }
        gnext += (size_t)PF * 16;
    }
    #pragma unroll
    for (int u = 0; u < PF; ++u)
        gru_step(pf[u], wr, wz, wn, bhr, bhz, bhn, hs, hcur);

    if (l == 0) {
        float acc = b_lin[0];
        #pragma unroll
        for (int k = 0; k < 16; ++k) acc += hs[k] * W_lin[k];
        out[b] = acc;
    }
    if (l < GHID) out[B + b * GHID + l] = hcur;
}

extern "C" void kernel_launch(void* const* d_in, const int* in_sizes, int n_in,
                              void* d_out, int out_size, void* d_ws, size_t ws_size,
                              hipStream_t stream) {
    const float* x      = (const float*)d_in[0];
    const int*   ei     = (const int*)d_in[1];
    // d_in[2] edge_attr: unused (edge_dim=None)
    const float* W_gat  = (const float*)d_in[3];
    const float* att_s  = (const float*)d_in[4];
    const float* att_d  = (const float*)d_in[5];
    const float* b_gat  = (const float*)d_in[6];
    const float* W_ih   = (const float*)d_in[7];
    const float* W_hh   = (const float*)d_in[8];
    const float* b_ih   = (const float*)d_in[9];
    const float* b_hh   = (const float*)d_in[10];
    const float* W_lin  = (const float*)d_in[11];
    const float* b_lin  = (const float*)d_in[12];
    float* out = (float*)d_out;

    int N = in_sizes[0] / F_IN;       // 65536
    int E = in_sizes[1] / 2;          // 1048576
    int Etot = E + N;                 // self-loops appended
    int B = N / T_SEQ;                // 32

    float* ws = (float*)d_ws;
    float* xp     = ws;                                   // N*64
    float* a_src  = xp + (size_t)N * 64;                  // N*8
    float* a_dst  = a_src + (size_t)N * 8;                // N*8
    float* denom  = a_dst + (size_t)N * 8;                // N*8
    float* agg    = denom + (size_t)N * 8;                // N*64
    float* gi4    = xp;   // aliases xp: xp dead after k4, k5 reads only agg/denom

    // zero denom + agg (contiguous): 2 + 16 MB
    hipMemsetAsync(denom, 0, (size_t)N * 72 * sizeof(float), stream);

    k1_xp<<<N / 4, 256, 0, stream>>>(x, W_gat, att_s, att_d, xp, a_src, a_dst);
    {
        long long tot = (long long)Etot * 64;
        int blocks = (int)((tot + 255) / 256);
        k4_agg<<<blocks, 256, 0, stream>>>(ei, E, Etot, a_src, a_dst, xp, denom, agg);
    }
    k5_gi<<<N / 16, 256, 0, stream>>>(agg, denom, b_gat, W_ih, b_ih, gi4);
    k6_gru<<<B / 8, 512, 0, stream>>>(gi4, W_hh, b_hh, W_lin, b_lin, out, B);
}

// Round 8
// 865.921 us; speedup vs baseline: 1.4944x; 1.4933x over previous
//
#include <hip/hip_runtime.h>
#include <stdint.h>

#define HEADS 8
#define DIM 8
#define HD 64
#define F_IN 128
#define T_SEQ 2048
#define GHID 16

// K1: xp = x @ W_gat  [N,64]; a_src[n,h] = sum_d xp[n,h,d]*att_src[h,d]; same a_dst.
__global__ __launch_bounds__(256) void k1_xp(
        const float* __restrict__ x, const float* __restrict__ Wg,
        const float* __restrict__ att_s, const float* __restrict__ att_d,
        float* __restrict__ xp, float* __restrict__ a_src, float* __restrict__ a_dst) {
    __shared__ float Wl[F_IN * HD];      // 32 KB
    __shared__ float xs[4][F_IN];        // 2 KB
    __shared__ float atts[HD], attd[HD];
    int t = threadIdx.x;
    for (int i = t * 4; i < F_IN * HD; i += 256 * 4)
        *(float4*)&Wl[i] = *(const float4*)&Wg[i];
    if (t < HD) { atts[t] = att_s[t]; attd[t] = att_d[t]; }
    int n0 = blockIdx.x * 4;
    {
        int ln = t >> 6, k = t & 63;
        *(float2*)&xs[ln][k * 2] = *(const float2*)&x[(size_t)(n0 + ln) * F_IN + k * 2];
    }
    __syncthreads();
    int ln = t >> 6, k = t & 63;
    float acc = 0.f;
    #pragma unroll 8
    for (int f = 0; f < F_IN; ++f) acc += xs[ln][f] * Wl[f * HD + k];
    int n = n0 + ln;
    xp[(size_t)n * HD + k] = acc;
    float ps = acc * atts[k];
    float pd = acc * attd[k];
    #pragma unroll
    for (int off = 1; off < 8; off <<= 1) {
        ps += __shfl_xor(ps, off);
        pd += __shfl_xor(pd, off);
    }
    if ((k & 7) == 0) {
        a_src[n * HEADS + (k >> 3)] = ps;
        a_dst[n * HEADS + (k >> 3)] = pd;
    }
}

// K4 (fused softmax-denom + aggregation, no max-subtraction):
// per edge: e = exp(leakyrelu(a_src[s]+a_dst[d])); denom[d][h] += e;
// agg[d][k] += xp[s][k] * e.   64 lanes per edge.
__global__ __launch_bounds__(256) void k4_agg(
        const int* __restrict__ ei, int E, int Etot,
        const float* __restrict__ a_src, const float* __restrict__ a_dst,
        const float* __restrict__ xp, float* __restrict__ denom,
        float* __restrict__ agg) {
    int t = blockIdx.x * 256 + threadIdx.x;
    int e = t >> 6;
    if (e >= Etot) return;
    int k = t & 63, h = k >> 3;
    int s, d;
    if (e < E) { s = ei[e]; d = ei[E + e]; } else { s = d = e - E; }
    float a = a_src[(size_t)s * 8 + h] + a_dst[(size_t)d * 8 + h];
    a = a > 0.f ? a : 0.2f * a;
    float ew = __expf(a);
    if ((k & 7) == 0) atomicAdd(&denom[(size_t)d * 8 + h], ew);
    float v = xp[(size_t)s * 64 + k];
    atomicAdd(&agg[(size_t)d * 64 + k], v * ew);
}

// K5: feat = relu(agg/denom + b_gat); gi4[n][j] = float4(i_r, i_z, i_n, 0)
// Packed layout so k6 does ONE dwordx4 load per step per lane.
__global__ __launch_bounds__(256) void k5_gi(
        const float* __restrict__ agg, const float* __restrict__ denom,
        const float* __restrict__ b_gat,
        const float* __restrict__ W_ih, const float* __restrict__ b_ih,
        float* __restrict__ gi4) {
    __shared__ float Wl[48 * 65];
    __shared__ float fl[16][65];
    __shared__ float bg[64], bi[48];
    int t = threadIdx.x;
    for (int i = t; i < 48 * 64; i += 256) Wl[(i >> 6) * 65 + (i & 63)] = W_ih[i];
    if (t < 64) bg[t] = b_gat[t];
    if (t < 48) bi[t] = b_ih[t];
    int n0 = blockIdx.x * 16;
    __syncthreads();
    for (int i = t; i < 16 * 64; i += 256) {
        int ln = i >> 6, k = i & 63;
        int n = n0 + ln;
        float den = denom[(size_t)n * 8 + (k >> 3)] + 1e-16f;
        float v = agg[(size_t)n * 64 + k] / den + bg[k];
        fl[ln][k] = v > 0.f ? v : 0.f;
    }
    __syncthreads();
    for (int o = t; o < 16 * 48; o += 256) {
        int ln = o / 48, g = o % 48;
        float acc = bi[g];
        #pragma unroll 8
        for (int f = 0; f < 64; ++f) acc += fl[ln][f] * Wl[g * 65 + f];
        int j = g & 15, gate = g >> 4;
        gi4[(size_t)(n0 + ln) * 64 + j * 4 + gate] = acc;
    }
}

// One GRU step. g = (i_r, i_z, i_n, pad) for this lane's unit j.
// bias+input folded into accumulator init (off the h-dependency chain).
__device__ __forceinline__ void gru_step(
        const float4 g, const float* __restrict__ wr, const float* __restrict__ wz,
        const float* __restrict__ wn, float bhr, float bhz, float bhn,
        float* hs, float& hcur) {
    float r0 = bhr + g.x, r1 = 0.f, r2 = 0.f, r3 = 0.f;
    float z0 = bhz + g.y, z1 = 0.f, z2 = 0.f, z3 = 0.f;
    float n0 = bhn,       n1 = 0.f, n2 = 0.f, n3 = 0.f;
    #pragma unroll
    for (int k = 0; k < 16; k += 4) {
        r0 = fmaf(wr[k],     hs[k],     r0);
        r1 = fmaf(wr[k + 1], hs[k + 1], r1);
        r2 = fmaf(wr[k + 2], hs[k + 2], r2);
        r3 = fmaf(wr[k + 3], hs[k + 3], r3);
        z0 = fmaf(wz[k],     hs[k],     z0);
        z1 = fmaf(wz[k + 1], hs[k + 1], z1);
        z2 = fmaf(wz[k + 2], hs[k + 2], z2);
        z3 = fmaf(wz[k + 3], hs[k + 3], z3);
        n0 = fmaf(wn[k],     hs[k],     n0);
        n1 = fmaf(wn[k + 1], hs[k + 1], n1);
        n2 = fmaf(wn[k + 2], hs[k + 2], n2);
        n3 = fmaf(wn[k + 3], hs[k + 3], n3);
    }
    float rpre = (r0 + r1) + (r2 + r3);
    float zpre = (z0 + z1) + (z2 + z3);
    float npre = (n0 + n1) + (n2 + n3);
    float r = 1.f / (1.f + __expf(-rpre));
    float z = 1.f / (1.f + __expf(-zpre));
    float np = g.z + r * npre;
    np = fminf(fmaxf(np, -15.f), 15.f);
    float e2 = __expf(-2.f * np);
    float nn = (1.f - e2) / (1.f + e2);
    hcur = fmaf(z, hcur - nn, nn);           // (1-z)*n + z*h
    #pragma unroll
    for (int k = 0; k < 16; ++k)
        hs[k] = __int_as_float(
            __builtin_amdgcn_readlane(__float_as_int(hcur), k));
}

// K6 v5: 1 wave per block, 32 blocks -> 1 wave/CU (whole SIMD per chain).
// One dwordx4 gi load per step; PF=16 rotating prefetch (each value consumed
// ~16 steps ~ 4000+ cy after issue -> even HBM latency fully hidden).
// h broadcast via v_readlane (SGPRs); no LDS, no barriers.
__global__ __launch_bounds__(64) void k6_gru(
        const float* __restrict__ gi4, const float* __restrict__ W_hh,
        const float* __restrict__ b_hh, const float* __restrict__ W_lin,
        const float* __restrict__ b_lin, float* __restrict__ out, int B) {
    int l = threadIdx.x;
    int b = blockIdx.x;
    int j = l & 15;

    float wr[16], wz[16], wn[16];
    #pragma unroll
    for (int k = 0; k < 16; ++k) {
        wr[k] = W_hh[j * 16 + k];
        wz[k] = W_hh[(16 + j) * 16 + k];
        wn[k] = W_hh[(32 + j) * 16 + k];
    }
    float bhr = b_hh[j], bhz = b_hh[16 + j], bhn = b_hh[32 + j];

    const float4* gp = (const float4*)gi4 + (size_t)b * T_SEQ * 16 + j;

    float hcur = 0.f;
    float hs[16];
    #pragma unroll
    for (int k = 0; k < 16; ++k) hs[k] = 0.f;

    const int PF = 16;
    float4 pf[PF];
    #pragma unroll
    for (int i = 0; i < PF; ++i) pf[i] = gp[(size_t)i * 16];
    const float4* gnext = gp + (size_t)PF * 16;

    for (int c = 0; c < T_SEQ - PF; c += PF) {
        #pragma unroll
        for (int u = 0; u < PF; ++u) {
            float4 g = pf[u];
            pf[u] = gnext[(size_t)u * 16];
            gru_step(g, wr, wz, wn, bhr, bhz, bhn, hs, hcur);
        }
        gnext += (size_t)PF * 16;
    }
    #pragma unroll
    for (int u = 0; u < PF; ++u)
        gru_step(pf[u], wr, wz, wn, bhr, bhz, bhn, hs, hcur);

    if (l == 0) {
        float acc = b_lin[0];
        #pragma unroll
        for (int k = 0; k < 16; ++k) acc += hs[k] * W_lin[k];
        out[b] = acc;
    }
    if (l < GHID) out[B + b * GHID + l] = hcur;
}

extern "C" void kernel_launch(void* const* d_in, const int* in_sizes, int n_in,
                              void* d_out, int out_size, void* d_ws, size_t ws_size,
                              hipStream_t stream) {
    const float* x      = (const float*)d_in[0];
    const int*   ei     = (const int*)d_in[1];
    // d_in[2] edge_attr: unused (edge_dim=None)
    const float* W_gat  = (const float*)d_in[3];
    const float* att_s  = (const float*)d_in[4];
    const float* att_d  = (const float*)d_in[5];
    const float* b_gat  = (const float*)d_in[6];
    const float* W_ih   = (const float*)d_in[7];
    const float* W_hh   = (const float*)d_in[8];
    const float* b_ih   = (const float*)d_in[9];
    const float* b_hh   = (const float*)d_in[10];
    const float* W_lin  = (const float*)d_in[11];
    const float* b_lin  = (const float*)d_in[12];
    float* out = (float*)d_out;

    int N = in_sizes[0] / F_IN;       // 65536
    int E = in_sizes[1] / 2;          // 1048576
    int Etot = E + N;                 // self-loops appended
    int B = N / T_SEQ;                // 32

    float* ws = (float*)d_ws;
    float* xp     = ws;                                   // N*64
    float* a_src  = xp + (size_t)N * 64;                  // N*8
    float* a_dst  = a_src + (size_t)N * 8;                // N*8
    float* denom  = a_dst + (size_t)N * 8;                // N*8
    float* agg    = denom + (size_t)N * 8;                // N*64
    float* gi4    = xp;   // aliases xp: xp dead after k4, k5 reads only agg/denom

    // zero denom + agg (contiguous): 2 + 16 MB
    hipMemsetAsync(denom, 0, (size_t)N * 72 * sizeof(float), stream);

    k1_xp<<<N / 4, 256, 0, stream>>>(x, W_gat, att_s, att_d, xp, a_src, a_dst);
    {
        long long tot = (long long)Etot * 64;
        int blocks = (int)((tot + 255) / 256);
        k4_agg<<<blocks, 256, 0, stream>>>(ei, E, Etot, a_src, a_dst, xp, denom, agg);
    }
    k5_gi<<<N / 16, 256, 0, stream>>>(agg, denom, b_gat, W_ih, b_ih, gi4);
    k6_gru<<<B, 64, 0, stream>>>(gi4, W_hh, b_hh, W_lin, b_lin, out, B);
}

// Round 9
// 862.146 us; speedup vs baseline: 1.5009x; 1.0044x over previous
//
#include <hip/hip_runtime.h>
#include <stdint.h>

#define HEADS 8
#define DIM 8
#define HD 64
#define F_IN 128
#define T_SEQ 2048
#define GHID 16

// K1: xp = x @ W_gat  [N,64]; a_src[n,h] = sum_d xp[n,h,d]*att_src[h,d]; same a_dst.
__global__ __launch_bounds__(256) void k1_xp(
        const float* __restrict__ x, const float* __restrict__ Wg,
        const float* __restrict__ att_s, const float* __restrict__ att_d,
        float* __restrict__ xp, float* __restrict__ a_src, float* __restrict__ a_dst) {
    __shared__ float Wl[F_IN * HD];      // 32 KB
    __shared__ float xs[4][F_IN];        // 2 KB
    __shared__ float atts[HD], attd[HD];
    int t = threadIdx.x;
    for (int i = t * 4; i < F_IN * HD; i += 256 * 4)
        *(float4*)&Wl[i] = *(const float4*)&Wg[i];
    if (t < HD) { atts[t] = att_s[t]; attd[t] = att_d[t]; }
    int n0 = blockIdx.x * 4;
    {
        int ln = t >> 6, k = t & 63;
        *(float2*)&xs[ln][k * 2] = *(const float2*)&x[(size_t)(n0 + ln) * F_IN + k * 2];
    }
    __syncthreads();
    int ln = t >> 6, k = t & 63;
    float acc = 0.f;
    #pragma unroll 8
    for (int f = 0; f < F_IN; ++f) acc += xs[ln][f] * Wl[f * HD + k];
    int n = n0 + ln;
    xp[(size_t)n * HD + k] = acc;
    float ps = acc * atts[k];
    float pd = acc * attd[k];
    #pragma unroll
    for (int off = 1; off < 8; off <<= 1) {
        ps += __shfl_xor(ps, off);
        pd += __shfl_xor(pd, off);
    }
    if ((k & 7) == 0) {
        a_src[n * HEADS + (k >> 3)] = ps;
        a_dst[n * HEADS + (k >> 3)] = pd;
    }
}

// K4 (fused softmax-denom + aggregation, no max-subtraction):
// per edge: e = exp(leakyrelu(a_src[s]+a_dst[d])); denom[d][h] += e;
// agg[d][k] += xp[s][k] * e.   64 lanes per edge.
__global__ __launch_bounds__(256) void k4_agg(
        const int* __restrict__ ei, int E, int Etot,
        const float* __restrict__ a_src, const float* __restrict__ a_dst,
        const float* __restrict__ xp, float* __restrict__ denom,
        float* __restrict__ agg) {
    int t = blockIdx.x * 256 + threadIdx.x;
    int e = t >> 6;
    if (e >= Etot) return;
    int k = t & 63, h = k >> 3;
    int s, d;
    if (e < E) { s = ei[e]; d = ei[E + e]; } else { s = d = e - E; }
    float a = a_src[(size_t)s * 8 + h] + a_dst[(size_t)d * 8 + h];
    a = a > 0.f ? a : 0.2f * a;
    float ew = __expf(a);
    if ((k & 7) == 0) atomicAdd(&denom[(size_t)d * 8 + h], ew);
    float v = xp[(size_t)s * 64 + k];
    atomicAdd(&agg[(size_t)d * 64 + k], v * ew);
}

// K5: feat = relu(agg/denom + b_gat); gi4[n][j] = float4(i_r, i_z, i_n, 0)
// Packed layout so k6 does ONE dwordx4 load per step per lane.
__global__ __launch_bounds__(256) void k5_gi(
        const float* __restrict__ agg, const float* __restrict__ denom,
        const float* __restrict__ b_gat,
        const float* __restrict__ W_ih, const float* __restrict__ b_ih,
        float* __restrict__ gi4) {
    __shared__ float Wl[48 * 65];
    __shared__ float fl[16][65];
    __shared__ float bg[64], bi[48];
    int t = threadIdx.x;
    for (int i = t; i < 48 * 64; i += 256) Wl[(i >> 6) * 65 + (i & 63)] = W_ih[i];
    if (t < 64) bg[t] = b_gat[t];
    if (t < 48) bi[t] = b_ih[t];
    int n0 = blockIdx.x * 16;
    __syncthreads();
    for (int i = t; i < 16 * 64; i += 256) {
        int ln = i >> 6, k = i & 63;
        int n = n0 + ln;
        float den = denom[(size_t)n * 8 + (k >> 3)] + 1e-16f;
        float v = agg[(size_t)n * 64 + k] / den + bg[k];
        fl[ln][k] = v > 0.f ? v : 0.f;
    }
    __syncthreads();
    for (int o = t; o < 16 * 48; o += 256) {
        int ln = o / 48, g = o % 48;
        float acc = bi[g];
        #pragma unroll 8
        for (int f = 0; f < 64; ++f) acc += fl[ln][f] * Wl[g * 65 + f];
        int j = g & 15, gate = g >> 4;
        gi4[(size_t)(n0 + ln) * 64 + j * 4 + gate] = acc;
    }
}

// FMA-only Pade(7,7) tanh: max err ~1.5e-5 on [-4,4]; clamped tail err <= 6.6e-4.
// Removes v_exp from the GRU critical chain (only v_rcp remains).
__device__ __forceinline__ float tanh_pade(float x) {
    x = fminf(fmaxf(x, -4.f), 4.f);
    float x2 = x * x;
    float num = x * fmaf(x2, fmaf(x2, (x2 + 378.f), 17325.f), 135135.f);
    float den = fmaf(x2, fmaf(x2, fmaf(x2, 28.f, 3150.f), 62370.f), 135135.f);
    return num * __builtin_amdgcn_rcpf(den);
}
__device__ __forceinline__ float sigmoid_pade(float x) {
    return fmaf(0.5f, tanh_pade(0.5f * x), 0.5f);
}

// One GRU step. g = (i_r, i_z, i_n, pad) for this lane's unit j.
// bias+input folded into accumulator init; z-path (z*h, 1-z) computed in
// parallel with the tanh chain; activations are FMA+rcp rationals.
__device__ __forceinline__ void gru_step(
        const float4 g, const float* __restrict__ wr, const float* __restrict__ wz,
        const float* __restrict__ wn, float bhr, float bhz, float bhn,
        float* hs, float& hcur) {
    float r0 = bhr + g.x, r1 = 0.f, r2 = 0.f, r3 = 0.f;
    float z0 = bhz + g.y, z1 = 0.f, z2 = 0.f, z3 = 0.f;
    float n0 = bhn,       n1 = 0.f, n2 = 0.f, n3 = 0.f;
    #pragma unroll
    for (int k = 0; k < 16; k += 4) {
        r0 = fmaf(wr[k],     hs[k],     r0);
        r1 = fmaf(wr[k + 1], hs[k + 1], r1);
        r2 = fmaf(wr[k + 2], hs[k + 2], r2);
        r3 = fmaf(wr[k + 3], hs[k + 3], r3);
        z0 = fmaf(wz[k],     hs[k],     z0);
        z1 = fmaf(wz[k + 1], hs[k + 1], z1);
        z2 = fmaf(wz[k + 2], hs[k + 2], z2);
        z3 = fmaf(wz[k + 3], hs[k + 3], z3);
        n0 = fmaf(wn[k],     hs[k],     n0);
        n1 = fmaf(wn[k + 1], hs[k + 1], n1);
        n2 = fmaf(wn[k + 2], hs[k + 2], n2);
        n3 = fmaf(wn[k + 3], hs[k + 3], n3);
    }
    float rpre = (r0 + r1) + (r2 + r3);
    float zpre = (z0 + z1) + (z2 + z3);
    float npre = (n0 + n1) + (n2 + n3);
    float r = sigmoid_pade(rpre);
    float z = sigmoid_pade(zpre);
    float zh  = z * hcur;          // off the tanh chain
    float omz = 1.f - z;
    float np = fmaf(r, npre, g.z);
    float nn = tanh_pade(np);
    hcur = fmaf(omz, nn, zh);      // (1-z)*n + z*h
    #pragma unroll
    for (int k = 0; k < 16; ++k)
        hs[k] = __int_as_float(
            __builtin_amdgcn_readlane(__float_as_int(hcur), k));
}

// K6 v6: 1 wave per block, 32 blocks -> 1 wave/CU. One dwordx4 gi load per
// step, PF=8 rotating prefetch. h broadcast via v_readlane; rational
// activations (no v_exp on the critical chain). No LDS, no barriers.
__global__ __launch_bounds__(64) void k6_gru(
        const float* __restrict__ gi4, const float* __restrict__ W_hh,
        const float* __restrict__ b_hh, const float* __restrict__ W_lin,
        const float* __restrict__ b_lin, float* __restrict__ out, int B) {
    int l = threadIdx.x;
    int b = blockIdx.x;
    int j = l & 15;

    float wr[16], wz[16], wn[16];
    #pragma unroll
    for (int k = 0; k < 16; ++k) {
        wr[k] = W_hh[j * 16 + k];
        wz[k] = W_hh[(16 + j) * 16 + k];
        wn[k] = W_hh[(32 + j) * 16 + k];
    }
    float bhr = b_hh[j], bhz = b_hh[16 + j], bhn = b_hh[32 + j];

    const float4* gp = (const float4*)gi4 + (size_t)b * T_SEQ * 16 + j;

    float hcur = 0.f;
    float hs[16];
    #pragma unroll
    for (int k = 0; k < 16; ++k) hs[k] = 0.f;

    const int PF = 8;
    float4 pf[PF];
    #pragma unroll
    for (int i = 0; i < PF; ++i) pf[i] = gp[(size_t)i * 16];
    const float4* gnext = gp + (size_t)PF * 16;

    for (int c = 0; c < T_SEQ - PF; c += PF) {
        #pragma unroll
        for (int u = 0; u < PF; ++u) {
            float4 g = pf[u];
            pf[u] = gnext[(size_t)u * 16];
            gru_step(g, wr, wz, wn, bhr, bhz, bhn, hs, hcur);
        }
        gnext += (size_t)PF * 16;
    }
    #pragma unroll
    for (int u = 0; u < PF; ++u)
        gru_step(pf[u], wr, wz, wn, bhr, bhz, bhn, hs, hcur);

    if (l == 0) {
        float acc = b_lin[0];
        #pragma unroll
        for (int k = 0; k < 16; ++k) acc += hs[k] * W_lin[k];
        out[b] = acc;
    }
    if (l < GHID) out[B + b * GHID + l] = hcur;
}

extern "C" void kernel_launch(void* const* d_in, const int* in_sizes, int n_in,
                              void* d_out, int out_size, void* d_ws, size_t ws_size,
                              hipStream_t stream) {
    const float* x      = (const float*)d_in[0];
    const int*   ei     = (const int*)d_in[1];
    // d_in[2] edge_attr: unused (edge_dim=None)
    const float* W_gat  = (const float*)d_in[3];
    const float* att_s  = (const float*)d_in[4];
    const float* att_d  = (const float*)d_in[5];
    const float* b_gat  = (const float*)d_in[6];
    const float* W_ih   = (const float*)d_in[7];
    const float* W_hh   = (const float*)d_in[8];
    const float* b_ih   = (const float*)d_in[9];
    const float* b_hh   = (const float*)d_in[10];
    const float* W_lin  = (const float*)d_in[11];
    const float* b_lin  = (const float*)d_in[12];
    float* out = (float*)d_out;

    int N = in_sizes[0] / F_IN;       // 65536
    int E = in_sizes[1] / 2;          // 1048576
    int Etot = E + N;                 // self-loops appended
    int B = N / T_SEQ;                // 32

    float* ws = (float*)d_ws;
    float* xp     = ws;                                   // N*64
    float* a_src  = xp + (size_t)N * 64;                  // N*8
    float* a_dst  = a_src + (size_t)N * 8;                // N*8
    float* denom  = a_dst + (size_t)N * 8;                // N*8
    float* agg    = denom + (size_t)N * 8;                // N*64
    float* gi4    = xp;   // aliases xp: xp dead after k4, k5 reads only agg/denom

    // zero denom + agg (contiguous): 2 + 16 MB
    hipMemsetAsync(denom, 0, (size_t)N * 72 * sizeof(float), stream);

    k1_xp<<<N / 4, 256, 0, stream>>>(x, W_gat, att_s, att_d, xp, a_src, a_dst);
    {
        long long tot = (long long)Etot * 64;
        int blocks = (int)((tot + 255) / 256);
        k4_agg<<<blocks, 256, 0, stream>>>(ei, E, Etot, a_src, a_dst, xp, denom, agg);
    }
    k5_gi<<<N / 16, 256, 0, stream>>>(agg, denom, b_gat, W_ih, b_ih, gi4);
    k6_gru<<<B, 64, 0, stream>>>(gi4, W_hh, b_hh, W_lin, b_lin, out, B);
}